// Round 7
// baseline (229.424 us; speedup 1.0000x reference)
//
#include <hip/hip_runtime.h>

// NonLocalBlock: B=8, C=512, N=4096 (64x64), CR=128.
// ws layout (bf16): ab [8][4096][256] (emb_a 0..127, emb_b 128..255, token-major)
//                   gC [8][128][4096] (channel-major)
//                   yt [8][4096][128] (token-major)
//                   wi [384][512]  (bf16 w_in, from k_prep; emb_a rows pre-scaled by log2e)
//                   wo [512][128]  (bf16 w_out, from k_prep)

typedef __attribute__((ext_vector_type(8))) short short8;
typedef __attribute__((ext_vector_type(4))) float f32x4;
typedef __attribute__((ext_vector_type(16))) float f32x16;
typedef __attribute__((ext_vector_type(2))) unsigned int uint2v;

__device__ inline unsigned bfr(float f) {   // bf16 round-half-up, result in high half
  union { float f; unsigned u; } v; v.f = f;
  return v.u + 0x8000u;
}
__device__ inline unsigned short f2bf(float f) { return (unsigned short)(bfr(f) >> 16); }
// pack2(a,b) -> [bf16(a) lo, bf16(b) hi] : 2 adds + 1 v_perm_b32
__device__ inline unsigned pack2(float a, float b) {
  return __builtin_amdgcn_perm(bfr(b), bfr(a), 0x07060302u);
}
// single-op packed f32->bf16 (RNE) for the hot loop
__device__ inline unsigned cvtpk(float a, float b) {
  unsigned r;
  asm("v_cvt_pk_bf16_f32 %0, %1, %2" : "=v"(r) : "v"(a), "v"(b));
  return r;
}
// XOR-swizzled LDS index (halves). 16B granules: phys = g ^ (row&7).
__device__ inline int sw(int row, int col, int stride_halves) {
  return row * stride_halves + ((((col >> 3) ^ (row & 7)) << 3) | (col & 7));
}
// async global->LDS DMA, 16B per lane; lds dest = wave-uniform base + lane*16
__device__ inline void load_lds16(const void* g, void* l) {
  __builtin_amdgcn_global_load_lds(
      (const __attribute__((address_space(1))) unsigned int*)g,
      (__attribute__((address_space(3))) unsigned int*)l, 16, 0, 0);
}

// ---------------- kernel 0: weight precompute fp32 -> bf16 -------------------------
// emb_a rows (0..127 of w_in) pre-scaled by log2(e): scores come out in log2 domain,
// so k_attn uses v_exp_f32 directly (exp2) with no per-element multiply. Exact:
// exp2(s*log2e) == exp(s), softmax unchanged.
__global__ __launch_bounds__(256) void k_prep(const float* __restrict__ w_in,
                                              const float* __restrict__ w_out,
                                              unsigned short* __restrict__ wi,
                                              unsigned short* __restrict__ wo) {
  int i = blockIdx.x * 256 + threadIdx.x;   // 8 floats per thread; 32768 threads
  const float* src;
  unsigned short* dst;
  int base;
  float s = 1.0f;
  if (i < 24576) {
    src = w_in;  dst = wi; base = i * 8;                  // 196608 elems
    if (base < 128 * 512) s = 1.4426950408889634f;        // emb_a rows only
  } else {
    src = w_out; dst = wo; base = (i - 24576) * 8;        // 65536 elems
  }
  float4 d0 = *(const float4*)&src[base];
  float4 d1 = *(const float4*)&src[base + 4];
  d0.x *= s; d0.y *= s; d0.z *= s; d0.w *= s;
  d1.x *= s; d1.y *= s; d1.z *= s; d1.w *= s;
  uint4 p;
  p.x = pack2(d0.x, d0.y); p.y = pack2(d0.z, d0.w);
  p.z = pack2(d1.x, d1.y); p.w = pack2(d1.z, d1.w);
  *(uint4*)&dst[base] = p;
}

// ---------------- kernel 1: in-projection GEMM (M=384, K=512, N=4096, per batch) ----
// ONE block per 64-token tile computes ALL 384 outputs (round-4 structure, kept).
__global__ __launch_bounds__(256, 2) void k_proj(const float* __restrict__ x,
                                                 const unsigned short* __restrict__ wi,
                                                 unsigned short* __restrict__ ab,
                                                 unsigned short* __restrict__ gC) {
  __shared__ unsigned short A_lds[384 * 64];   // [384 o][64 c], swizzled (48 KB)
  __shared__ unsigned short B_lds[64 * 64];    // [64 n][64 c], swizzled (8 KB)
  const int t = threadIdx.x;
  const int lane = t & 63;
  const int w = t >> 6;
  const int l15 = lane & 15;
  const int quad = lane >> 4;
  const int n0 = blockIdx.x * 64;
  const int b = blockIdx.y;
  const int ch8g = t >> 5;        // 0..7: 8-channel group for B staging
  const int tp = t & 31;          // 0..31: token pair

  f32x4 acc[6][4];
#pragma unroll
  for (int i = 0; i < 6; i++)
#pragma unroll
    for (int j = 0; j < 4; j++) acc[i][j] = (f32x4)0.f;

  // prologue: B panel for k0=0
  float2 d[8];
#pragma unroll
  for (int j = 0; j < 8; j++)
    d[j] = *(const float2*)&x[((size_t)(b * 512 + ch8g * 8 + j)) * 4096 + n0 + tp * 2];

  for (int k0 = 0; k0 < 512; k0 += 64) {
    // stage A via DMA: 96 rows per wave, 12 calls x 8 rows (128 B rows)
#pragma unroll
    for (int j = 0; j < 12; j++) {
      int row = w * 96 + j * 8 + (lane >> 3);
      int gs = (lane & 7) ^ (row & 7);
      load_lds16(&wi[(size_t)row * 512 + k0 + gs * 8],
                 (void*)&A_lds[(w * 96 + j * 8) * 64]);
    }
    // stage B micro-transpose from regs: 8 channels x 2 tokens per thread
#pragma unroll
    for (int i = 0; i < 2; i++) {
      int r = tp * 2 + i;
      uint4 pv;
      if (i == 0) {
        pv.x = pack2(d[0].x, d[1].x); pv.y = pack2(d[2].x, d[3].x);
        pv.z = pack2(d[4].x, d[5].x); pv.w = pack2(d[6].x, d[7].x);
      } else {
        pv.x = pack2(d[0].y, d[1].y); pv.y = pack2(d[2].y, d[3].y);
        pv.z = pack2(d[4].y, d[5].y); pv.w = pack2(d[6].y, d[7].y);
      }
      *(uint4*)&B_lds[sw(r, ch8g * 8, 64)] = pv;
    }
    // prefetch next B panel (overlaps barrier + MFMA below)
    if (k0 + 64 < 512) {
#pragma unroll
      for (int j = 0; j < 8; j++)
        d[j] = *(const float2*)&x[((size_t)(b * 512 + k0 + 64 + ch8g * 8 + j)) * 4096 + n0 + tp * 2];
    }
    __syncthreads();   // drains DMA (vmcnt) + B ds_writes (lgkm)
#pragma unroll
    for (int kk = 0; kk < 64; kk += 32) {
      short8 a[6];
#pragma unroll
      for (int m = 0; m < 6; m++)
        a[m] = *(const short8*)&A_lds[sw(w * 96 + m * 16 + l15, kk + quad * 8, 64)];
#pragma unroll
      for (int ns = 0; ns < 4; ns++) {
        short8 bb = *(const short8*)&B_lds[sw(ns * 16 + l15, kk + quad * 8, 64)];
#pragma unroll
        for (int m = 0; m < 6; m++)
          acc[m][ns] = __builtin_amdgcn_mfma_f32_16x16x32_bf16(a[m], bb, acc[m][ns], 0, 0, 0);
      }
    }
    __syncthreads();
  }
  // epilogue: o < 256 -> ab (packed uint2), o >= 256 -> gC (channel-major scalar).
#pragma unroll
  for (int m = 0; m < 6; m++) {
    int o = w * 96 + m * 16 + quad * 4;
    if (o < 256) {
#pragma unroll
      for (int ns = 0; ns < 4; ns++) {
        int n = n0 + ns * 16 + l15;
        uint2 p;
        p.x = pack2(acc[m][ns][0], acc[m][ns][1]);
        p.y = pack2(acc[m][ns][2], acc[m][ns][3]);
        *(uint2*)&ab[((size_t)(b * 4096 + n)) * 256 + o] = p;
      }
    } else {
      int og = o - 256;
#pragma unroll
      for (int ns = 0; ns < 4; ns++) {
        int n = n0 + ns * 16 + l15;
#pragma unroll
        for (int r = 0; r < 4; r++)
          gC[((size_t)(b * 128 + og + r)) * 4096 + n] = f2bf(acc[m][ns][r]);
      }
    }
  }
}

// ---------------- kernel 2: flash attention, 512 threads, chunked LDS layout -------
// Round-6 structure (8 waves = 2 key-halves x 4 q-tiles, shared staging, 82 us) with
// FRAGMENT-CONTIGUOUS K/V placement: each 16 KB tile = 16 chunks of 1 KB, one chunk
// == one MFMA fragment read laid out lane-linear. Every ds_read_b128 is then
// uniform-base + lane*16 (conflict-free m134 baseline, offset folds to immediate);
// the old row-major layout had bank = f(granule) only (row stride % 128B == 0) ->
// structural 4-way conflict (the 8.45M counter). DMA dest stays linear; the per-lane
// SOURCE address encodes the placement (global_load_lds src is per-lane arbitrary).
// K chunk (wr,ks): lane l -> K[wr*32+(l&31)][ks*16+(l>>5)*8 ..+8]
// V chunk (ct,wr,f): lane l -> V[ct*32+(l&31)][key granule (wr*4+f*2+(l>>5))*8]
__global__ __launch_bounds__(512, 2) void k_attn(const unsigned short* __restrict__ ab,
                                                 const unsigned short* __restrict__ gC,
                                                 unsigned short* __restrict__ yt) {
  __shared__ uint4 smem4[65536 / 16];                       // 64 KB
  unsigned short* smem_h = (unsigned short*)smem4;
  // K bufs: halves [0, 8192), [8192, 16384);  V bufs: [16384, 24576), [24576, 32768)
  float* Obuf = (float*)smem4;                              // epilogue [64 q][129 c]
  float* lsumbuf = (float*)((char*)smem4 + 33024);          // [64]
  unsigned* Pbuf = (unsigned*)((char*)smem4 + 33280);       // [64 q][65]

  const int t = threadIdx.x;
  const int lane = t & 63;
  const int w = t >> 6;        // 0..7
  const int wr = w & 1;        // key half
  const int wc = w >> 1;       // q tile (0..3), 32 q each
  const int l31 = lane & 31;
  const int h = lane >> 5;
  const int b = blockIdx.x & 7;            // XCD-locality: batch -> XCD
  const int q0 = (blockIdx.x >> 3) * 128;

  // Q fragments (B operand), loop-invariant
  short8 qf[8];
  {
    const unsigned short* qp = &ab[((size_t)(b * 4096 + q0 + wc * 32 + l31)) * 256 + h * 8];
#pragma unroll
    for (int ks = 0; ks < 8; ks++) qf[ks] = *(const short8*)&qp[ks * 16];
  }

  // staging: wave w stages K chunks {2w, 2w+1} and V chunks {2w, 2w+1}
  auto dma_tile = [&](int kt, int buf) {
    unsigned short* Kb = smem_h + buf * 8192;
    unsigned short* Vb = smem_h + 16384 + buf * 8192;
#pragma unroll
    for (int j = 0; j < 2; j++) {
      int ck = w * 2 + j;                  // K chunk: wr_c = ck>>3, ks_c = ck&7
      int wrc = ck >> 3, ksc = ck & 7;
      load_lds16(&ab[((size_t)(b * 4096 + kt + wrc * 32 + l31)) * 256 + 128 + ksc * 16 + h * 8],
                 (void*)&Kb[ck * 512]);
    }
#pragma unroll
    for (int j = 0; j < 2; j++) {
      int cv = w * 2 + j;                  // V chunk: ct_c = cv>>2, wr_c = (cv>>1)&1, f_c = cv&1
      int ctc = cv >> 2, wrc = (cv >> 1) & 1, fc = cv & 1;
      load_lds16(&gC[((size_t)(b * 128 + ctc * 32 + l31)) * 4096 + kt + (wrc * 4 + fc * 2 + h) * 8],
                 (void*)&Vb[cv * 512]);
    }
  };

  f32x16 O[4];
#pragma unroll
  for (int i = 0; i < 4; i++) O[i] = (f32x16)0.f;
  float ls0 = 0.f, ls1 = 0.f, ls2 = 0.f, ls3 = 0.f;   // 4-way lsum (break dep chain)

  dma_tile(0, 0);
  __syncthreads();

  for (int it = 0; it < 64; ++it) {
    if (it < 63) dma_tile((it + 1) * 64, (it + 1) & 1);   // prefetch next tile (async)
    const unsigned short* Kc = smem_h + (it & 1) * 8192;
    const unsigned short* Vc = smem_h + 16384 + (it & 1) * 8192;

    // S^T = K · Q^T : D[key 32][q 32]  (scores already in log2 domain)
    f32x16 accS = (f32x16)0.f;
    __builtin_amdgcn_s_setprio(1);
#pragma unroll
    for (int ks = 0; ks < 8; ks++) {
      short8 ak = *(const short8*)&Kc[(wr * 8 + ks) * 512 + lane * 8];
      accS = __builtin_amdgcn_mfma_f32_32x32x16_bf16(ak, qf[ks], accS, 0, 0, 0);
    }
    __builtin_amdgcn_s_setprio(0);

    // exp2 (no max; scores bounded, log2e pre-folded) + 4-way lsum partials
    float ps[16];
#pragma unroll
    for (int r = 0; r < 16; r++) ps[r] = __builtin_amdgcn_exp2f(accS[r]);
    ls0 += ps[0] + ps[4];  ls1 += ps[1] + ps[5];
    ls2 += ps[2] + ps[6];  ls3 += ps[3] + ps[7];
    ls0 += ps[8] + ps[12]; ls1 += ps[9] + ps[13];
    ls2 += ps[10] + ps[14]; ls3 += ps[11] + ps[15];
    unsigned u[8];
#pragma unroll
    for (int i = 0; i < 8; i++) u[i] = cvtpk(ps[2 * i], ps[2 * i + 1]);

    // P^T B-frags in-register via permlane32_swap (words 0,2 of A-fragment)
    short8 pfrag[2];
#pragma unroll
    for (int f = 0; f < 2; f++) {
      uint2v r02 = __builtin_amdgcn_permlane32_swap(u[4 * f + 0], u[4 * f + 2], false, false);
      uint2v r13 = __builtin_amdgcn_permlane32_swap(u[4 * f + 1], u[4 * f + 3], false, false);
      union { unsigned uu[4]; short8 s; } cv;
      cv.uu[0] = r02[0]; cv.uu[1] = r13[0]; cv.uu[2] = r02[1]; cv.uu[3] = r13[1];
      pfrag[f] = cv.s;
    }

    // O^T[c][q] += V · P^T over this wave's 32 keys
    __builtin_amdgcn_s_setprio(1);
#pragma unroll
    for (int ct = 0; ct < 4; ct++) {
#pragma unroll
      for (int f = 0; f < 2; f++) {
        short8 av = *(const short8*)&Vc[(ct * 4 + wr * 2 + f) * 512 + lane * 8];
        O[ct] = __builtin_amdgcn_mfma_f32_32x32x16_bf16(av, pfrag[f], O[ct], 0, 0, 0);
      }
    }
    __builtin_amdgcn_s_setprio(0);
    __syncthreads();   // drains DMA (in flight during whole compute) + LDS reads
  }

  // ---- epilogue: two passes of 64 q (wc pairs), merge key-half partials ----
  float lsum = (ls0 + ls1) + (ls2 + ls3);
  lsum += __shfl_xor(lsum, 32);
#pragma unroll
  for (int p = 0; p < 2; ++p) {
    const bool act = (wc >> 1) == p;        // this wave's q-range is in this pass
    const int q = (wc & 1) * 32 + l31;      // q within the 64-row pass window
    if (act && wr == 0) {
#pragma unroll
      for (int ct = 0; ct < 4; ct++)
#pragma unroll
        for (int r = 0; r < 16; r++) {
          int c = ct * 32 + (r & 3) + 8 * (r >> 2) + 4 * h;
          Obuf[q * 129 + c] = O[ct][r];
        }
      if (h == 0) lsumbuf[q] = lsum;
    }
    __syncthreads();
    if (act && wr == 1) {
      float linv = 1.f / (lsum + lsumbuf[q]);
#pragma unroll
      for (int ct = 0; ct < 4; ct++)
#pragma unroll
        for (int r = 0; r < 16; r += 2) {
          int c = ct * 32 + (r & 3) + 8 * (r >> 2) + 4 * h;
          float v0 = (Obuf[q * 129 + c] + O[ct][r]) * linv;
          float v1 = (Obuf[q * 129 + c + 1] + O[ct][r + 1]) * linv;
          Pbuf[q * 65 + (c >> 1)] = pack2(v0, v1);
        }
    }
    __syncthreads();
    {
      int qq = t >> 3, seg = t & 7;        // 512 threads cover 64 q rows, 32 B each
      unsigned* yrow = (unsigned*)&yt[((size_t)(b * 4096 + q0 + p * 64 + qq)) * 128];
#pragma unroll
      for (int i = 0; i < 2; i++) {
        int base = qq * 65 + seg * 8 + i * 4;
        uint4 v;
        v.x = Pbuf[base + 0];
        v.y = Pbuf[base + 1];
        v.z = Pbuf[base + 2];
        v.w = Pbuf[base + 3];
        *(uint4*)&yrow[seg * 8 + i * 4] = v;
      }
    }
    // no extra barrier needed: pass-1 writes touch Obuf/lsumbuf only after the
    // barrier that already separates them from pass-0's Obuf reads; Pbuf writes
    // of pass 1 are fenced by the first barrier inside the next iteration.
  }
}

// ---------------- kernel 3: out-projection GEMM (M=512, K=128, N=4096) + residual ---
// Both operands bf16 in ws -> staged 100% by DMA. Flat grid with b=id&7: all 256
// blocks of batch b land on XCD b -> yt (1 MB) + wo L2-resident per XCD.
__global__ __launch_bounds__(256) void k_out(const float* __restrict__ x,
                                             const unsigned short* __restrict__ wo,
                                             const unsigned short* __restrict__ yt,
                                             float* __restrict__ out) {
  __shared__ unsigned short A_lds[128 * 128];  // [128 o][128 c], swizzled (32 KB)
  __shared__ unsigned short B_lds[64 * 128];   // [64 n][128 c], swizzled (16 KB)
  const int t = threadIdx.x;
  const int lane = t & 63;
  const int w = t >> 6;
  const int l15 = lane & 15;
  const int quad = lane >> 4;
  const int id = blockIdx.x;
  const int b = id & 7;                    // XCD-locality: batch -> XCD
  const int rest = id >> 3;                // 0..255
  const int o0 = (rest & 3) * 128;
  const int n0 = (rest >> 2) * 64;

  // A DMA: 8 calls x 4 rows (256 B rows)
#pragma unroll
  for (int j = 0; j < 8; j++) {
    int row = w * 32 + j * 4 + (lane >> 4);
    int gs = (lane & 15) ^ (row & 7);
    load_lds16(&wo[(size_t)(o0 + row) * 128 + gs * 8],
               (void*)&A_lds[(w * 32 + j * 4) * 128]);
  }
  // B DMA: 4 calls x 4 rows
#pragma unroll
  for (int j = 0; j < 4; j++) {
    int row = w * 16 + j * 4 + (lane >> 4);
    int gs = (lane & 15) ^ (row & 7);
    load_lds16(&yt[((size_t)(b * 4096 + n0 + row)) * 128 + gs * 8],
               (void*)&B_lds[(w * 16 + j * 4) * 128]);
  }
  __syncthreads();

  f32x4 acc[2][4];
#pragma unroll
  for (int i = 0; i < 2; i++)
#pragma unroll
    for (int j = 0; j < 4; j++) acc[i][j] = (f32x4)0.f;
#pragma unroll
  for (int ks = 0; ks < 4; ks++) {
    short8 a0 = *(const short8*)&A_lds[sw(w * 32 + l15, ks * 32 + quad * 8, 128)];
    short8 a1 = *(const short8*)&A_lds[sw(w * 32 + 16 + l15, ks * 32 + quad * 8, 128)];
#pragma unroll
    for (int ns = 0; ns < 4; ns++) {
      short8 bb = *(const short8*)&B_lds[sw(ns * 16 + l15, ks * 32 + quad * 8, 128)];
      acc[0][ns] = __builtin_amdgcn_mfma_f32_16x16x32_bf16(a0, bb, acc[0][ns], 0, 0, 0);
      acc[1][ns] = __builtin_amdgcn_mfma_f32_16x16x32_bf16(a1, bb, acc[1][ns], 0, 0, 0);
    }
  }
#pragma unroll
  for (int ms = 0; ms < 2; ms++) {
    int o = o0 + w * 32 + ms * 16 + quad * 4;
#pragma unroll
    for (int ns = 0; ns < 4; ns++) {
      int n = n0 + ns * 16 + l15;
#pragma unroll
      for (int r = 0; r < 4; r++) {
        size_t off = ((size_t)(b * 512 + o + r)) * 4096 + n;
        out[off] = x[off] + acc[ms][ns][r];
      }
    }
  }
}

extern "C" void kernel_launch(void* const* d_in, const int* in_sizes, int n_in,
                              void* d_out, int out_size, void* d_ws, size_t ws_size,
                              hipStream_t stream) {
  const float* x = (const float*)d_in[0];
  const float* w_in = (const float*)d_in[1];
  const float* w_out = (const float*)d_in[2];
  float* out = (float*)d_out;

  unsigned short* ab = (unsigned short*)d_ws;                 // 8*4096*256
  unsigned short* gC = ab + (size_t)8 * 4096 * 256;           // 8*128*4096
  unsigned short* yt = gC + (size_t)8 * 128 * 4096;           // 8*4096*128
  unsigned short* wi = yt + (size_t)8 * 4096 * 128;           // 384*512
  unsigned short* wo = wi + (size_t)384 * 512;                // 512*128

  k_prep<<<128, 256, 0, stream>>>(w_in, w_out, wi, wo);
  k_proj<<<dim3(64, 8), 256, 0, stream>>>(x, wi, ab, gC);
  k_attn<<<dim3(256), 512, 0, stream>>>(ab, gC, yt);
  k_out<<<2048, 256, 0, stream>>>(x, wo, yt, out);
}

// Round 8
// 215.434 us; speedup vs baseline: 1.0649x; 1.0649x over previous
//
#include <hip/hip_runtime.h>

// NonLocalBlock: B=8, C=512, N=4096 (64x64), CR=128.
// ws layout (bf16):
//   aq [8][4096][128]      emb_a token-major (Q reads; log2e pre-folded via wi)
//   Kf [8][64][8192]       K fragment-image per 64-key tile: chunk ck=wrc*8+ksc,
//                          lane l=(h*32+l31), elem e: emb_b[chan ksc*16+h*8+e][key wrc*32+l31]
//   Vf [8][64][8192]       V fragment-image: chunk cv=ct*4+(g8>>1), lane (g8&1)*32+(c&31),
//                          elem key&7: g[chan c][key], g8=key>>3
//   yt [8][4096][128]      attention output token-major
//   wi [384][512], wo [512][128]
// k_attn DMA is then linear on BOTH sides: src = chunk base + lane*16 (1024 B
// contiguous per call), dest = LDS linear; LDS reads are chunk*512+lane*8 =
// conflict-free. The fragment permutation lives in k_proj's epilogue stores,
// which were already scattered 8B/2B writes of the same data.

typedef __attribute__((ext_vector_type(8))) short short8;
typedef __attribute__((ext_vector_type(4))) float f32x4;
typedef __attribute__((ext_vector_type(16))) float f32x16;
typedef __attribute__((ext_vector_type(2))) unsigned int uint2v;

__device__ inline unsigned bfr(float f) {   // bf16 round-half-up, result in high half
  union { float f; unsigned u; } v; v.f = f;
  return v.u + 0x8000u;
}
__device__ inline unsigned short f2bf(float f) { return (unsigned short)(bfr(f) >> 16); }
// pack2(a,b) -> [bf16(a) lo, bf16(b) hi] : 2 adds + 1 v_perm_b32
__device__ inline unsigned pack2(float a, float b) {
  return __builtin_amdgcn_perm(bfr(b), bfr(a), 0x07060302u);
}
// single-op packed f32->bf16 (RNE) for the hot loop
__device__ inline unsigned cvtpk(float a, float b) {
  unsigned r;
  asm("v_cvt_pk_bf16_f32 %0, %1, %2" : "=v"(r) : "v"(a), "v"(b));
  return r;
}
// XOR-swizzled LDS index (halves). 16B granules: phys = g ^ (row&7).
__device__ inline int sw(int row, int col, int stride_halves) {
  return row * stride_halves + ((((col >> 3) ^ (row & 7)) << 3) | (col & 7));
}
// async global->LDS DMA, 16B per lane; lds dest = wave-uniform base + lane*16
__device__ inline void load_lds16(const void* g, void* l) {
  __builtin_amdgcn_global_load_lds(
      (const __attribute__((address_space(1))) unsigned int*)g,
      (__attribute__((address_space(3))) unsigned int*)l, 16, 0, 0);
}

// ---------------- kernel 0: weight precompute fp32 -> bf16 -------------------------
// emb_a rows (0..127 of w_in) pre-scaled by log2(e): scores come out in log2 domain,
// so k_attn uses v_exp_f32 directly (exp2) with no per-element multiply. Exact:
// exp2(s*log2e) == exp(s), softmax unchanged.
__global__ __launch_bounds__(256) void k_prep(const float* __restrict__ w_in,
                                              const float* __restrict__ w_out,
                                              unsigned short* __restrict__ wi,
                                              unsigned short* __restrict__ wo) {
  int i = blockIdx.x * 256 + threadIdx.x;   // 8 floats per thread; 32768 threads
  const float* src;
  unsigned short* dst;
  int base;
  float s = 1.0f;
  if (i < 24576) {
    src = w_in;  dst = wi; base = i * 8;                  // 196608 elems
    if (base < 128 * 512) s = 1.4426950408889634f;        // emb_a rows only
  } else {
    src = w_out; dst = wo; base = (i - 24576) * 8;        // 65536 elems
  }
  float4 d0 = *(const float4*)&src[base];
  float4 d1 = *(const float4*)&src[base + 4];
  d0.x *= s; d0.y *= s; d0.z *= s; d0.w *= s;
  d1.x *= s; d1.y *= s; d1.z *= s; d1.w *= s;
  uint4 p;
  p.x = pack2(d0.x, d0.y); p.y = pack2(d0.z, d0.w);
  p.z = pack2(d1.x, d1.y); p.w = pack2(d1.z, d1.w);
  *(uint4*)&dst[base] = p;
}

// ---------------- kernel 1: in-projection GEMM (M=384, K=512, N=4096, per batch) ----
// ONE block per 64-token tile computes ALL 384 outputs (round-4 structure). The
// epilogue now writes K/V directly in the attn fragment-image layout (see header).
__global__ __launch_bounds__(256, 2) void k_proj(const float* __restrict__ x,
                                                 const unsigned short* __restrict__ wi,
                                                 unsigned short* __restrict__ aq,
                                                 unsigned short* __restrict__ Kf,
                                                 unsigned short* __restrict__ Vf) {
  __shared__ unsigned short A_lds[384 * 64];   // [384 o][64 c], swizzled (48 KB)
  __shared__ unsigned short B_lds[64 * 64];    // [64 n][64 c], swizzled (8 KB)
  const int t = threadIdx.x;
  const int lane = t & 63;
  const int w = t >> 6;
  const int l15 = lane & 15;
  const int quad = lane >> 4;
  const int tl = blockIdx.x;      // 64-token tile index
  const int n0 = tl * 64;
  const int b = blockIdx.y;
  const int ch8g = t >> 5;        // 0..7: 8-channel group for B staging
  const int tp = t & 31;          // 0..31: token pair

  f32x4 acc[6][4];
#pragma unroll
  for (int i = 0; i < 6; i++)
#pragma unroll
    for (int j = 0; j < 4; j++) acc[i][j] = (f32x4)0.f;

  // prologue: B panel for k0=0
  float2 d[8];
#pragma unroll
  for (int j = 0; j < 8; j++)
    d[j] = *(const float2*)&x[((size_t)(b * 512 + ch8g * 8 + j)) * 4096 + n0 + tp * 2];

  for (int k0 = 0; k0 < 512; k0 += 64) {
    // stage A via DMA: 96 rows per wave, 12 calls x 8 rows (128 B rows)
#pragma unroll
    for (int j = 0; j < 12; j++) {
      int row = w * 96 + j * 8 + (lane >> 3);
      int gs = (lane & 7) ^ (row & 7);
      load_lds16(&wi[(size_t)row * 512 + k0 + gs * 8],
                 (void*)&A_lds[(w * 96 + j * 8) * 64]);
    }
    // stage B micro-transpose from regs: 8 channels x 2 tokens per thread
#pragma unroll
    for (int i = 0; i < 2; i++) {
      int r = tp * 2 + i;
      uint4 pv;
      if (i == 0) {
        pv.x = pack2(d[0].x, d[1].x); pv.y = pack2(d[2].x, d[3].x);
        pv.z = pack2(d[4].x, d[5].x); pv.w = pack2(d[6].x, d[7].x);
      } else {
        pv.x = pack2(d[0].y, d[1].y); pv.y = pack2(d[2].y, d[3].y);
        pv.z = pack2(d[4].y, d[5].y); pv.w = pack2(d[6].y, d[7].y);
      }
      *(uint4*)&B_lds[sw(r, ch8g * 8, 64)] = pv;
    }
    // prefetch next B panel (overlaps barrier + MFMA below)
    if (k0 + 64 < 512) {
#pragma unroll
      for (int j = 0; j < 8; j++)
        d[j] = *(const float2*)&x[((size_t)(b * 512 + k0 + 64 + ch8g * 8 + j)) * 4096 + n0 + tp * 2];
    }
    __syncthreads();   // drains DMA (vmcnt) + B ds_writes (lgkm)
#pragma unroll
    for (int kk = 0; kk < 64; kk += 32) {
      short8 a[6];
#pragma unroll
      for (int m = 0; m < 6; m++)
        a[m] = *(const short8*)&A_lds[sw(w * 96 + m * 16 + l15, kk + quad * 8, 64)];
#pragma unroll
      for (int ns = 0; ns < 4; ns++) {
        short8 bb = *(const short8*)&B_lds[sw(ns * 16 + l15, kk + quad * 8, 64)];
#pragma unroll
        for (int m = 0; m < 6; m++)
          acc[m][ns] = __builtin_amdgcn_mfma_f32_16x16x32_bf16(a[m], bb, acc[m][ns], 0, 0, 0);
      }
    }
    __syncthreads();
  }
  // epilogue: o<128 -> aq (token-major); 128..255 -> Kf fragment-image (uint2);
  //           o>=256 -> Vf fragment-image (scalar). Boundaries are wave-uniform.
  const size_t tbase = ((size_t)(b * 64 + tl)) * 8192;
#pragma unroll
  for (int m = 0; m < 6; m++) {
    int o = w * 96 + m * 16 + quad * 4;
    if (o < 128) {
#pragma unroll
      for (int ns = 0; ns < 4; ns++) {
        int n = n0 + ns * 16 + l15;
        uint2 p;
        p.x = pack2(acc[m][ns][0], acc[m][ns][1]);
        p.y = pack2(acc[m][ns][2], acc[m][ns][3]);
        *(uint2*)&aq[((size_t)(b * 4096 + n)) * 128 + o] = p;
      }
    } else if (o < 256) {
      int c = o - 128;                       // 0..127, aligned 4
      int ksc = c >> 4, hk = (c >> 3) & 1, e0 = c & 7;   // e0 in {0,4}
#pragma unroll
      for (int ns = 0; ns < 4; ns++) {
        int key = ns * 16 + l15;             // 0..63 within tile
        int ck = (key >> 5) * 8 + ksc;
        int lane_k = hk * 32 + (key & 31);
        uint2 p;
        p.x = pack2(acc[m][ns][0], acc[m][ns][1]);
        p.y = pack2(acc[m][ns][2], acc[m][ns][3]);
        *(uint2*)&Kf[tbase + ck * 512 + lane_k * 8 + e0] = p;
      }
    } else {
      int cb = o - 256;                      // 0..127, aligned 4
#pragma unroll
      for (int ns = 0; ns < 4; ns++) {
        int key = ns * 16 + l15;
        int g8 = key >> 3;                   // key granule 0..7
        int e = key & 7;
        size_t kb = tbase + (size_t)((g8 & 1) * 32) * 8 + e + (size_t)(g8 >> 1) * 512;
#pragma unroll
        for (int r = 0; r < 4; r++) {
          int c = cb + r;
          Vf[kb + (size_t)(c >> 5) * 4 * 512 + (size_t)(c & 31) * 8] = f2bf(acc[m][ns][r]);
        }
      }
    }
  }
}

// ---------------- kernel 2: flash attention, 512 threads, fragment-image DMA -------
// Round-6 structure (8 waves = 2 key-halves x 4 q-tiles, shared staging) + round-7
// conflict-free chunked LDS, now with LINEAR DMA: Kf/Vf are stored as the exact LDS
// image, so each global_load_lds reads 1024 B contiguous (src = base + lane*16).
// LDS reads: chunk*512 + lane*8 -> uniform+lane*16 B, conflict-free, offset folds
// to immediate. Grid 256 flat, b=id&7 (batch -> XCD L2 residency).
__global__ __launch_bounds__(512, 2) void k_attn(const unsigned short* __restrict__ aq,
                                                 const unsigned short* __restrict__ Kf,
                                                 const unsigned short* __restrict__ Vf,
                                                 unsigned short* __restrict__ yt) {
  __shared__ uint4 smem4[65536 / 16];                       // 64 KB
  unsigned short* smem_h = (unsigned short*)smem4;
  // K bufs: halves [0, 8192), [8192, 16384);  V bufs: [16384, 24576), [24576, 32768)
  float* Obuf = (float*)smem4;                              // epilogue [64 q][129 c]
  float* lsumbuf = (float*)((char*)smem4 + 33024);          // [64]
  unsigned* Pbuf = (unsigned*)((char*)smem4 + 33280);       // [64 q][65]

  const int t = threadIdx.x;
  const int lane = t & 63;
  const int w = t >> 6;        // 0..7
  const int wr = w & 1;        // key half
  const int wc = w >> 1;       // q tile (0..3), 32 q each
  const int l31 = lane & 31;
  const int h = lane >> 5;
  const int b = blockIdx.x & 7;            // XCD-locality: batch -> XCD
  const int q0 = (blockIdx.x >> 3) * 128;

  // Q fragments (B operand), loop-invariant
  short8 qf[8];
  {
    const unsigned short* qp = &aq[((size_t)(b * 4096 + q0 + wc * 32 + l31)) * 128 + h * 8];
#pragma unroll
    for (int ks = 0; ks < 8; ks++) qf[ks] = *(const short8*)&qp[ks * 16];
  }

  // staging: wave w stages chunks {2w, 2w+1} of K and V; src fully linear.
  auto dma_tile = [&](int tl, int buf) {
    unsigned short* Kb = smem_h + buf * 8192;
    unsigned short* Vb = smem_h + 16384 + buf * 8192;
    const unsigned short* Ks = &Kf[((size_t)(b * 64 + tl)) * 8192];
    const unsigned short* Vs = &Vf[((size_t)(b * 64 + tl)) * 8192];
#pragma unroll
    for (int j = 0; j < 2; j++) {
      int ck = w * 2 + j;
      load_lds16(&Ks[ck * 512 + lane * 8], (void*)&Kb[ck * 512]);
      load_lds16(&Vs[ck * 512 + lane * 8], (void*)&Vb[ck * 512]);
    }
  };

  f32x16 O[4];
#pragma unroll
  for (int i = 0; i < 4; i++) O[i] = (f32x16)0.f;
  float ls0 = 0.f, ls1 = 0.f, ls2 = 0.f, ls3 = 0.f;   // 4-way lsum (break dep chain)

  dma_tile(0, 0);
  __syncthreads();

  for (int it = 0; it < 64; ++it) {
    if (it < 63) dma_tile(it + 1, (it + 1) & 1);   // prefetch next tile (async)
    const unsigned short* Kc = smem_h + (it & 1) * 8192;
    const unsigned short* Vc = smem_h + 16384 + (it & 1) * 8192;

    // S^T = K · Q^T : D[key 32][q 32]  (scores already in log2 domain)
    f32x16 accS = (f32x16)0.f;
    __builtin_amdgcn_s_setprio(1);
#pragma unroll
    for (int ks = 0; ks < 8; ks++) {
      short8 ak = *(const short8*)&Kc[(wr * 8 + ks) * 512 + lane * 8];
      accS = __builtin_amdgcn_mfma_f32_32x32x16_bf16(ak, qf[ks], accS, 0, 0, 0);
    }
    __builtin_amdgcn_s_setprio(0);

    // exp2 (no max; scores bounded, log2e pre-folded) + 4-way lsum partials
    float ps[16];
#pragma unroll
    for (int r = 0; r < 16; r++) ps[r] = __builtin_amdgcn_exp2f(accS[r]);
    ls0 += ps[0] + ps[4];  ls1 += ps[1] + ps[5];
    ls2 += ps[2] + ps[6];  ls3 += ps[3] + ps[7];
    ls0 += ps[8] + ps[12]; ls1 += ps[9] + ps[13];
    ls2 += ps[10] + ps[14]; ls3 += ps[11] + ps[15];
    unsigned u[8];
#pragma unroll
    for (int i = 0; i < 8; i++) u[i] = cvtpk(ps[2 * i], ps[2 * i + 1]);

    // P^T B-frags in-register via permlane32_swap (words 0,2 of A-fragment)
    short8 pfrag[2];
#pragma unroll
    for (int f = 0; f < 2; f++) {
      uint2v r02 = __builtin_amdgcn_permlane32_swap(u[4 * f + 0], u[4 * f + 2], false, false);
      uint2v r13 = __builtin_amdgcn_permlane32_swap(u[4 * f + 1], u[4 * f + 3], false, false);
      union { unsigned uu[4]; short8 s; } cv;
      cv.uu[0] = r02[0]; cv.uu[1] = r13[0]; cv.uu[2] = r02[1]; cv.uu[3] = r13[1];
      pfrag[f] = cv.s;
    }

    // O^T[c][q] += V · P^T over this wave's 32 keys
    __builtin_amdgcn_s_setprio(1);
#pragma unroll
    for (int ct = 0; ct < 4; ct++) {
#pragma unroll
      for (int f = 0; f < 2; f++) {
        short8 av = *(const short8*)&Vc[(ct * 4 + wr * 2 + f) * 512 + lane * 8];
        O[ct] = __builtin_amdgcn_mfma_f32_32x32x16_bf16(av, pfrag[f], O[ct], 0, 0, 0);
      }
    }
    __builtin_amdgcn_s_setprio(0);
    __syncthreads();   // drains DMA (in flight during whole compute) + LDS reads
  }

  // ---- epilogue: two passes of 64 q (wc pairs), merge key-half partials ----
  float lsum = (ls0 + ls1) + (ls2 + ls3);
  lsum += __shfl_xor(lsum, 32);
#pragma unroll
  for (int p = 0; p < 2; ++p) {
    const bool act = (wc >> 1) == p;        // this wave's q-range is in this pass
    const int q = (wc & 1) * 32 + l31;      // q within the 64-row pass window
    if (act && wr == 0) {
#pragma unroll
      for (int ct = 0; ct < 4; ct++)
#pragma unroll
        for (int r = 0; r < 16; r++) {
          int c = ct * 32 + (r & 3) + 8 * (r >> 2) + 4 * h;
          Obuf[q * 129 + c] = O[ct][r];
        }
      if (h == 0) lsumbuf[q] = lsum;
    }
    __syncthreads();
    if (act && wr == 1) {
      float linv = 1.f / (lsum + lsumbuf[q]);
#pragma unroll
      for (int ct = 0; ct < 4; ct++)
#pragma unroll
        for (int r = 0; r < 16; r += 2) {
          int c = ct * 32 + (r & 3) + 8 * (r >> 2) + 4 * h;
          float v0 = (Obuf[q * 129 + c] + O[ct][r]) * linv;
          float v1 = (Obuf[q * 129 + c + 1] + O[ct][r + 1]) * linv;
          Pbuf[q * 65 + (c >> 1)] = pack2(v0, v1);
        }
    }
    __syncthreads();
    {
      int qq = t >> 3, seg = t & 7;        // 512 threads cover 64 q rows, 32 B each
      unsigned* yrow = (unsigned*)&yt[((size_t)(b * 4096 + q0 + p * 64 + qq)) * 128];
#pragma unroll
      for (int i = 0; i < 2; i++) {
        int base = qq * 65 + seg * 8 + i * 4;
        uint4 v;
        v.x = Pbuf[base + 0];
        v.y = Pbuf[base + 1];
        v.z = Pbuf[base + 2];
        v.w = Pbuf[base + 3];
        *(uint4*)&yrow[seg * 8 + i * 4] = v;
      }
    }
    // pass-1 Obuf/lsumbuf writes are separated from pass-0 reads by the barriers
    // above; Pbuf writes of pass 1 are fenced by the first barrier of iteration 1.
  }
}

// ---------------- kernel 3: out-projection GEMM (M=512, K=128, N=4096) + residual ---
// Both operands bf16 in ws -> staged 100% by DMA. Flat grid with b=id&7: all 256
// blocks of batch b land on XCD b -> yt (1 MB) + wo L2-resident per XCD.
__global__ __launch_bounds__(256) void k_out(const float* __restrict__ x,
                                             const unsigned short* __restrict__ wo,
                                             const unsigned short* __restrict__ yt,
                                             float* __restrict__ out) {
  __shared__ unsigned short A_lds[128 * 128];  // [128 o][128 c], swizzled (32 KB)
  __shared__ unsigned short B_lds[64 * 128];   // [64 n][128 c], swizzled (16 KB)
  const int t = threadIdx.x;
  const int lane = t & 63;
  const int w = t >> 6;
  const int l15 = lane & 15;
  const int quad = lane >> 4;
  const int id = blockIdx.x;
  const int b = id & 7;                    // XCD-locality: batch -> XCD
  const int rest = id >> 3;                // 0..255
  const int o0 = (rest & 3) * 128;
  const int n0 = (rest >> 2) * 64;

  // A DMA: 8 calls x 4 rows (256 B rows)
#pragma unroll
  for (int j = 0; j < 8; j++) {
    int row = w * 32 + j * 4 + (lane >> 4);
    int gs = (lane & 15) ^ (row & 7);
    load_lds16(&wo[(size_t)(o0 + row) * 128 + gs * 8],
               (void*)&A_lds[(w * 32 + j * 4) * 128]);
  }
  // B DMA: 4 calls x 4 rows
#pragma unroll
  for (int j = 0; j < 4; j++) {
    int row = w * 16 + j * 4 + (lane >> 4);
    int gs = (lane & 15) ^ (row & 7);
    load_lds16(&yt[((size_t)(b * 4096 + n0 + row)) * 128 + gs * 8],
               (void*)&B_lds[(w * 16 + j * 4) * 128]);
  }
  __syncthreads();

  f32x4 acc[2][4];
#pragma unroll
  for (int i = 0; i < 2; i++)
#pragma unroll
    for (int j = 0; j < 4; j++) acc[i][j] = (f32x4)0.f;
#pragma unroll
  for (int ks = 0; ks < 4; ks++) {
    short8 a0 = *(const short8*)&A_lds[sw(w * 32 + l15, ks * 32 + quad * 8, 128)];
    short8 a1 = *(const short8*)&A_lds[sw(w * 32 + 16 + l15, ks * 32 + quad * 8, 128)];
#pragma unroll
    for (int ns = 0; ns < 4; ns++) {
      short8 bb = *(const short8*)&B_lds[sw(ns * 16 + l15, ks * 32 + quad * 8, 128)];
      acc[0][ns] = __builtin_amdgcn_mfma_f32_16x16x32_bf16(a0, bb, acc[0][ns], 0, 0, 0);
      acc[1][ns] = __builtin_amdgcn_mfma_f32_16x16x32_bf16(a1, bb, acc[1][ns], 0, 0, 0);
    }
  }
#pragma unroll
  for (int ms = 0; ms < 2; ms++) {
    int o = o0 + w * 32 + ms * 16 + quad * 4;
#pragma unroll
    for (int ns = 0; ns < 4; ns++) {
      int n = n0 + ns * 16 + l15;
#pragma unroll
      for (int r = 0; r < 4; r++) {
        size_t off = ((size_t)(b * 512 + o + r)) * 4096 + n;
        out[off] = x[off] + acc[ms][ns][r];
      }
    }
  }
}

extern "C" void kernel_launch(void* const* d_in, const int* in_sizes, int n_in,
                              void* d_out, int out_size, void* d_ws, size_t ws_size,
                              hipStream_t stream) {
  const float* x = (const float*)d_in[0];
  const float* w_in = (const float*)d_in[1];
  const float* w_out = (const float*)d_in[2];
  float* out = (float*)d_out;

  unsigned short* aq = (unsigned short*)d_ws;                 // 8*4096*128
  unsigned short* Kf = aq + (size_t)8 * 4096 * 128;           // 8*64*8192
  unsigned short* Vf = Kf + (size_t)8 * 64 * 8192;            // 8*64*8192
  unsigned short* yt = Vf + (size_t)8 * 64 * 8192;            // 8*4096*128
  unsigned short* wi = yt + (size_t)8 * 4096 * 128;           // 384*512
  unsigned short* wo = wi + (size_t)384 * 512;                // 512*128

  k_prep<<<128, 256, 0, stream>>>(w_in, w_out, wi, wo);
  k_proj<<<dim3(64, 8), 256, 0, stream>>>(x, wi, aq, Kf, Vf);
  k_attn<<<dim3(256), 512, 0, stream>>>(aq, Kf, Vf, yt);
  k_out<<<2048, 256, 0, stream>>>(x, wo, yt, out);
}

// Round 10
// 211.365 us; speedup vs baseline: 1.0854x; 1.0193x over previous
//
#include <hip/hip_runtime.h>

// NonLocalBlock: B=8, C=512, N=4096 (64x64), CR=128.
// ws layout (bf16):
//   aq [8][4096][128]      emb_a token-major (Q reads; log2e pre-folded via wi)
//   Kf [8][64][8192]       K fragment-image per 64-key tile: chunk ck=wrc*8+ksc,
//                          lane l=(h*32+l31), elem e: emb_b[chan ksc*16+h*8+e][key wrc*32+l31]
//   Vf [8][64][8192]       V fragment-image: chunk cv=ct*4+(g8>>1), lane (g8&1)*32+(c&31),
//                          elem key&7: g[chan c][key], g8=key>>3
//   yt [8][4096][128]      attention output token-major
//   wi [384][512], wo [512][128]
// k_attn DMA linear on BOTH sides (src chunk base + lane*16, dest LDS linear);
// LDS reads chunk*512+lane*8 conflict-free. Fragment permutation lives in k_proj.

typedef __attribute__((ext_vector_type(8))) short short8;
typedef __attribute__((ext_vector_type(4))) float f32x4;
typedef __attribute__((ext_vector_type(16))) float f32x16;
typedef __attribute__((ext_vector_type(2))) unsigned int uint2v;

__device__ inline unsigned bfr(float f) {   // bf16 round-half-up, result in high half
  union { float f; unsigned u; } v; v.f = f;
  return v.u + 0x8000u;
}
__device__ inline unsigned short f2bf(float f) { return (unsigned short)(bfr(f) >> 16); }
// pack2(a,b) -> [bf16(a) lo, bf16(b) hi] : 2 adds + 1 v_perm_b32
__device__ inline unsigned pack2(float a, float b) {
  return __builtin_amdgcn_perm(bfr(b), bfr(a), 0x07060302u);
}
// single-op packed f32->bf16 (RNE) for the hot loop
__device__ inline unsigned cvtpk(float a, float b) {
  unsigned r;
  asm("v_cvt_pk_bf16_f32 %0, %1, %2" : "=v"(r) : "v"(a), "v"(b));
  return r;
}
// XOR-swizzled LDS index (halves). 16B granules: phys = g ^ (row&7).
__device__ inline int sw(int row, int col, int stride_halves) {
  return row * stride_halves + ((((col >> 3) ^ (row & 7)) << 3) | (col & 7));
}
// async global->LDS DMA, 16B per lane; lds dest = wave-uniform base + lane*16
__device__ inline void load_lds16(const void* g, void* l) {
  __builtin_amdgcn_global_load_lds(
      (const __attribute__((address_space(1))) unsigned int*)g,
      (__attribute__((address_space(3))) unsigned int*)l, 16, 0, 0);
}

// ---------------- kernel 0: weight precompute fp32 -> bf16 -------------------------
// emb_a rows (0..127 of w_in) pre-scaled by log2(e): scores come out in log2 domain,
// so k_attn uses v_exp_f32 directly (exp2) with no per-element multiply. Exact:
// exp2(s*log2e) == exp(s), softmax unchanged.
__global__ __launch_bounds__(256) void k_prep(const float* __restrict__ w_in,
                                              const float* __restrict__ w_out,
                                              unsigned short* __restrict__ wi,
                                              unsigned short* __restrict__ wo) {
  int i = blockIdx.x * 256 + threadIdx.x;   // 8 floats per thread; 32768 threads
  const float* src;
  unsigned short* dst;
  int base;
  float s = 1.0f;
  if (i < 24576) {
    src = w_in;  dst = wi; base = i * 8;                  // 196608 elems
    if (base < 128 * 512) s = 1.4426950408889634f;        // emb_a rows only
  } else {
    src = w_out; dst = wo; base = (i - 24576) * 8;        // 65536 elems
  }
  float4 d0 = *(const float4*)&src[base];
  float4 d1 = *(const float4*)&src[base + 4];
  d0.x *= s; d0.y *= s; d0.z *= s; d0.w *= s;
  d1.x *= s; d1.y *= s; d1.z *= s; d1.w *= s;
  uint4 p;
  p.x = pack2(d0.x, d0.y); p.y = pack2(d0.z, d0.w);
  p.z = pack2(d1.x, d1.y); p.w = pack2(d1.z, d1.w);
  *(uint4*)&dst[base] = p;
}

// ---------------- kernel 1: in-projection GEMM (M=384, K=512, N=4096, per batch) ----
// ONE block per 64-token tile computes ALL 384 outputs (round-4 structure). The
// epilogue writes K/V directly in the attn fragment-image layout (see header).
__global__ __launch_bounds__(256, 2) void k_proj(const float* __restrict__ x,
                                                 const unsigned short* __restrict__ wi,
                                                 unsigned short* __restrict__ aq,
                                                 unsigned short* __restrict__ Kf,
                                                 unsigned short* __restrict__ Vf) {
  __shared__ unsigned short A_lds[384 * 64];   // [384 o][64 c], swizzled (48 KB)
  __shared__ unsigned short B_lds[64 * 64];    // [64 n][64 c], swizzled (8 KB)
  const int t = threadIdx.x;
  const int lane = t & 63;
  const int w = t >> 6;
  const int l15 = lane & 15;
  const int quad = lane >> 4;
  const int tl = blockIdx.x;      // 64-token tile index
  const int n0 = tl * 64;
  const int b = blockIdx.y;
  const int ch8g = t >> 5;        // 0..7: 8-channel group for B staging
  const int tp = t & 31;          // 0..31: token pair

  f32x4 acc[6][4];
#pragma unroll
  for (int i = 0; i < 6; i++)
#pragma unroll
    for (int j = 0; j < 4; j++) acc[i][j] = (f32x4)0.f;

  // prologue: B panel for k0=0
  float2 d[8];
#pragma unroll
  for (int j = 0; j < 8; j++)
    d[j] = *(const float2*)&x[((size_t)(b * 512 + ch8g * 8 + j)) * 4096 + n0 + tp * 2];

  for (int k0 = 0; k0 < 512; k0 += 64) {
    // stage A via DMA: 96 rows per wave, 12 calls x 8 rows (128 B rows)
#pragma unroll
    for (int j = 0; j < 12; j++) {
      int row = w * 96 + j * 8 + (lane >> 3);
      int gs = (lane & 7) ^ (row & 7);
      load_lds16(&wi[(size_t)row * 512 + k0 + gs * 8],
                 (void*)&A_lds[(w * 96 + j * 8) * 64]);
    }
    // stage B micro-transpose from regs: 8 channels x 2 tokens per thread
#pragma unroll
    for (int i = 0; i < 2; i++) {
      int r = tp * 2 + i;
      uint4 pv;
      if (i == 0) {
        pv.x = pack2(d[0].x, d[1].x); pv.y = pack2(d[2].x, d[3].x);
        pv.z = pack2(d[4].x, d[5].x); pv.w = pack2(d[6].x, d[7].x);
      } else {
        pv.x = pack2(d[0].y, d[1].y); pv.y = pack2(d[2].y, d[3].y);
        pv.z = pack2(d[4].y, d[5].y); pv.w = pack2(d[6].y, d[7].y);
      }
      *(uint4*)&B_lds[sw(r, ch8g * 8, 64)] = pv;
    }
    // prefetch next B panel (overlaps barrier + MFMA below)
    if (k0 + 64 < 512) {
#pragma unroll
      for (int j = 0; j < 8; j++)
        d[j] = *(const float2*)&x[((size_t)(b * 512 + k0 + 64 + ch8g * 8 + j)) * 4096 + n0 + tp * 2];
    }
    __syncthreads();   // drains DMA (vmcnt) + B ds_writes (lgkm)
#pragma unroll
    for (int kk = 0; kk < 64; kk += 32) {
      short8 a[6];
#pragma unroll
      for (int m = 0; m < 6; m++)
        a[m] = *(const short8*)&A_lds[sw(w * 96 + m * 16 + l15, kk + quad * 8, 64)];
#pragma unroll
      for (int ns = 0; ns < 4; ns++) {
        short8 bb = *(const short8*)&B_lds[sw(ns * 16 + l15, kk + quad * 8, 64)];
#pragma unroll
        for (int m = 0; m < 6; m++)
          acc[m][ns] = __builtin_amdgcn_mfma_f32_16x16x32_bf16(a[m], bb, acc[m][ns], 0, 0, 0);
      }
    }
    __syncthreads();
  }
  // epilogue: o<128 -> aq (token-major); 128..255 -> Kf fragment-image (uint2);
  //           o>=256 -> Vf fragment-image (scalar). Boundaries are wave-uniform.
  const size_t tbase = ((size_t)(b * 64 + tl)) * 8192;
#pragma unroll
  for (int m = 0; m < 6; m++) {
    int o = w * 96 + m * 16 + quad * 4;
    if (o < 128) {
#pragma unroll
      for (int ns = 0; ns < 4; ns++) {
        int n = n0 + ns * 16 + l15;
        uint2 p;
        p.x = pack2(acc[m][ns][0], acc[m][ns][1]);
        p.y = pack2(acc[m][ns][2], acc[m][ns][3]);
        *(uint2*)&aq[((size_t)(b * 4096 + n)) * 128 + o] = p;
      }
    } else if (o < 256) {
      int c = o - 128;                       // 0..127, aligned 4
      int ksc = c >> 4, hk = (c >> 3) & 1, e0 = c & 7;   // e0 in {0,4}
#pragma unroll
      for (int ns = 0; ns < 4; ns++) {
        int key = ns * 16 + l15;             // 0..63 within tile
        int ck = (key >> 5) * 8 + ksc;
        int lane_k = hk * 32 + (key & 31);
        uint2 p;
        p.x = pack2(acc[m][ns][0], acc[m][ns][1]);
        p.y = pack2(acc[m][ns][2], acc[m][ns][3]);
        *(uint2*)&Kf[tbase + ck * 512 + lane_k * 8 + e0] = p;
      }
    } else {
      int cb = o - 256;                      // 0..127, aligned 4
#pragma unroll
      for (int ns = 0; ns < 4; ns++) {
        int key = ns * 16 + l15;
        int g8 = key >> 3;                   // key granule 0..7
        int e = key & 7;
        size_t kb = tbase + (size_t)((g8 & 1) * 32) * 8 + e + (size_t)(g8 >> 1) * 512;
#pragma unroll
        for (int r = 0; r < 4; r++) {
          int c = cb + r;
          Vf[kb + (size_t)(c >> 5) * 4 * 512 + (size_t)(c & 31) * 8] = f2bf(acc[m][ns][r]);
        }
      }
    }
  }
}

// ---------------- kernel 2: flash attention, software-pipelined PV ----------------
// Round-8 structure (8 waves = 2 key-halves x 4 q-tiles, fragment-image linear DMA,
// conflict-free LDS) + PV DEFERRED ONE ITERATION: per iter the schedule is
// S_it (8 MFMA) -> PV_{it-1} (8 MFMA, pfP regs + V buf (it-1)&1) -> softmax_it.
// PV_{it-1} is independent of softmax_it, so softmax VALU overlaps the MFMA block
// instead of sitting between S and PV on the critical path (the round-8 convoy).
// Buffering (64 KB total, no overflow -- round-9 bug was an 80 KB ring in 64 KB):
//   K double-buffered, prefetched ONE AHEAD (tile it+1 staged at iter it);
//   V double-buffered, staged SAME-ITER (tile it staged at iter it, read at it+1):
//   write Vbuf it&1 vs read Vbuf (it-1)&1 never collide, and the written buf's
//   old tile (it-2) was consumed at iter it-1 before the barrier.
__global__ __launch_bounds__(512, 2) void k_attn(const unsigned short* __restrict__ aq,
                                                 const unsigned short* __restrict__ Kf,
                                                 const unsigned short* __restrict__ Vf,
                                                 unsigned short* __restrict__ yt) {
  __shared__ uint4 smem4[65536 / 16];                       // 64 KB
  unsigned short* smem_h = (unsigned short*)smem4;
  // K bufs (halves): [0,8192),[8192,16384); V bufs: [16384,24576),[24576,32768)
  float* Obuf = (float*)smem4;                              // epilogue [64 q][129 c]
  float* lsumbuf = (float*)((char*)smem4 + 33024);          // [64]
  unsigned* Pbuf = (unsigned*)((char*)smem4 + 33280);       // [64 q][65]

  const int t = threadIdx.x;
  const int lane = t & 63;
  const int w = t >> 6;        // 0..7
  const int wr = w & 1;        // key half
  const int wc = w >> 1;       // q tile (0..3), 32 q each
  const int l31 = lane & 31;
  const int h = lane >> 5;
  const int b = blockIdx.x & 7;            // XCD-locality: batch -> XCD
  const int q0 = (blockIdx.x >> 3) * 128;

  // Q fragments (B operand), loop-invariant
  short8 qf[8];
  {
    const unsigned short* qp = &aq[((size_t)(b * 4096 + q0 + wc * 32 + l31)) * 128 + h * 8];
#pragma unroll
    for (int ks = 0; ks < 8; ks++) qf[ks] = *(const short8*)&qp[ks * 16];
  }

  // staging: wave w stages chunks {2w, 2w+1}; src fully linear (1 KB per call).
  auto dma_k = [&](int tl, int buf) {
    unsigned short* Kb = smem_h + buf * 8192;
    const unsigned short* Ks = &Kf[((size_t)(b * 64 + tl)) * 8192];
#pragma unroll
    for (int j = 0; j < 2; j++) {
      int ck = w * 2 + j;
      load_lds16(&Ks[ck * 512 + lane * 8], (void*)&Kb[ck * 512]);
    }
  };
  auto dma_v = [&](int tl, int buf) {
    unsigned short* Vb = smem_h + 16384 + buf * 8192;
    const unsigned short* Vs = &Vf[((size_t)(b * 64 + tl)) * 8192];
#pragma unroll
    for (int j = 0; j < 2; j++) {
      int cv = w * 2 + j;
      load_lds16(&Vs[cv * 512 + lane * 8], (void*)&Vb[cv * 512]);
    }
  };

  f32x16 O[4];
#pragma unroll
  for (int i = 0; i < 4; i++) O[i] = (f32x16)0.f;
  float ls0 = 0.f, ls1 = 0.f, ls2 = 0.f, ls3 = 0.f;   // 4-way lsum (break dep chain)
  short8 pfP[2];                                       // P fragments of tile it-1

  auto computeS = [&](const unsigned short* Kc) -> f32x16 {
    f32x16 accS = (f32x16)0.f;
#pragma unroll
    for (int ks = 0; ks < 8; ks++) {
      short8 ak = *(const short8*)&Kc[(wr * 8 + ks) * 512 + lane * 8];
      accS = __builtin_amdgcn_mfma_f32_32x32x16_bf16(ak, qf[ks], accS, 0, 0, 0);
    }
    return accS;
  };
  auto computePV = [&](const unsigned short* Vc, const short8 pf[2]) {
#pragma unroll
    for (int ct = 0; ct < 4; ct++) {
#pragma unroll
      for (int f = 0; f < 2; f++) {
        short8 av = *(const short8*)&Vc[(ct * 4 + wr * 2 + f) * 512 + lane * 8];
        O[ct] = __builtin_amdgcn_mfma_f32_32x32x16_bf16(av, pf[f], O[ct], 0, 0, 0);
      }
    }
  };
  auto softmax = [&](const f32x16& accS, short8 pf[2]) {
    float ps[16];
#pragma unroll
    for (int r = 0; r < 16; r++) ps[r] = __builtin_amdgcn_exp2f(accS[r]);
    ls0 += ps[0] + ps[4];  ls1 += ps[1] + ps[5];
    ls2 += ps[2] + ps[6];  ls3 += ps[3] + ps[7];
    ls0 += ps[8] + ps[12]; ls1 += ps[9] + ps[13];
    ls2 += ps[10] + ps[14]; ls3 += ps[11] + ps[15];
    unsigned u[8];
#pragma unroll
    for (int i = 0; i < 8; i++) u[i] = cvtpk(ps[2 * i], ps[2 * i + 1]);
#pragma unroll
    for (int f = 0; f < 2; f++) {
      uint2v r02 = __builtin_amdgcn_permlane32_swap(u[4 * f + 0], u[4 * f + 2], false, false);
      uint2v r13 = __builtin_amdgcn_permlane32_swap(u[4 * f + 1], u[4 * f + 3], false, false);
      union { unsigned uu[4]; short8 s; } cv;
      cv.uu[0] = r02[0]; cv.uu[1] = r13[0]; cv.uu[2] = r02[1]; cv.uu[3] = r13[1];
      pf[f] = cv.s;
    }
  };

  // prologue: K tile 0 + V tile 0
  dma_k(0, 0);
  dma_v(0, 0);
  __syncthreads();

  // peeled iter 0: S_0 + softmax_0 (no PV yet); stage K tile 1
  {
    dma_k(1, 1);
    __builtin_amdgcn_s_setprio(1);
    f32x16 accS = computeS(smem_h);
    __builtin_amdgcn_s_setprio(0);
    softmax(accS, pfP);
    __syncthreads();
  }

  for (int it = 1; it < 64; ++it) {
    if (it < 63) dma_k(it + 1, (it + 1) & 1);   // K one ahead
    dma_v(it, it & 1);                          // V same-iter (read next iter)
    const unsigned short* Kc = smem_h + (it & 1) * 8192;
    const unsigned short* Vp = smem_h + 16384 + ((it - 1) & 1) * 8192;
    __builtin_amdgcn_s_setprio(1);
    f32x16 accS = computeS(Kc);      // S for tile it
    computePV(Vp, pfP);              // PV for tile it-1 (independent of softmax)
    __builtin_amdgcn_s_setprio(0);
    softmax(accS, pfP);              // VALU overlaps the PV MFMA block
    __syncthreads();                 // buffer reuse + DMA drain
  }

  // final PV for tile 63 (V buf 1; staged at it=63, drained by its barrier)
  {
    __builtin_amdgcn_s_setprio(1);
    computePV(smem_h + 16384 + 8192, pfP);
    __builtin_amdgcn_s_setprio(0);
  }
  __syncthreads();   // all V LDS reads done before epilogue aliases the region

  // ---- epilogue: two passes of 64 q (wc pairs), merge key-half partials ----
  float lsum = (ls0 + ls1) + (ls2 + ls3);
  lsum += __shfl_xor(lsum, 32);
#pragma unroll
  for (int p = 0; p < 2; ++p) {
    const bool act = (wc >> 1) == p;        // this wave's q-range is in this pass
    const int q = (wc & 1) * 32 + l31;      // q within the 64-row pass window
    if (act && wr == 0) {
#pragma unroll
      for (int ct = 0; ct < 4; ct++)
#pragma unroll
        for (int r = 0; r < 16; r++) {
          int c = ct * 32 + (r & 3) + 8 * (r >> 2) + 4 * h;
          Obuf[q * 129 + c] = O[ct][r];
        }
      if (h == 0) lsumbuf[q] = lsum;
    }
    __syncthreads();
    if (act && wr == 1) {
      float linv = 1.f / (lsum + lsumbuf[q]);
#pragma unroll
      for (int ct = 0; ct < 4; ct++)
#pragma unroll
        for (int r = 0; r < 16; r += 2) {
          int c = ct * 32 + (r & 3) + 8 * (r >> 2) + 4 * h;
          float v0 = (Obuf[q * 129 + c] + O[ct][r]) * linv;
          float v1 = (Obuf[q * 129 + c + 1] + O[ct][r + 1]) * linv;
          Pbuf[q * 65 + (c >> 1)] = pack2(v0, v1);
        }
    }
    __syncthreads();
    {
      int qq = t >> 3, seg = t & 7;        // 512 threads cover 64 q rows, 32 B each
      unsigned* yrow = (unsigned*)&yt[((size_t)(b * 4096 + q0 + p * 64 + qq)) * 128];
#pragma unroll
      for (int i = 0; i < 2; i++) {
        int base = qq * 65 + seg * 8 + i * 4;
        uint4 v;
        v.x = Pbuf[base + 0];
        v.y = Pbuf[base + 1];
        v.z = Pbuf[base + 2];
        v.w = Pbuf[base + 3];
        *(uint4*)&yrow[seg * 8 + i * 4] = v;
      }
    }
    // pass-1 Obuf/lsumbuf writes are separated from pass-0 reads by the barriers
    // above; Pbuf writes of pass 1 are fenced by the first barrier of iteration 1.
  }
}

// ---------------- kernel 3: out-projection GEMM (M=512, K=128, N=4096) + residual ---
// Both operands bf16 in ws -> staged 100% by DMA. Flat grid with b=id&7: all 256
// blocks of batch b land on XCD b -> yt (1 MB) + wo L2-resident per XCD.
__global__ __launch_bounds__(256) void k_out(const float* __restrict__ x,
                                             const unsigned short* __restrict__ wo,
                                             const unsigned short* __restrict__ yt,
                                             float* __restrict__ out) {
  __shared__ unsigned short A_lds[128 * 128];  // [128 o][128 c], swizzled (32 KB)
  __shared__ unsigned short B_lds[64 * 128];   // [64 n][128 c], swizzled (16 KB)
  const int t = threadIdx.x;
  const int lane = t & 63;
  const int w = t >> 6;
  const int l15 = lane & 15;
  const int quad = lane >> 4;
  const int id = blockIdx.x;
  const int b = id & 7;                    // XCD-locality: batch -> XCD
  const int rest = id >> 3;                // 0..255
  const int o0 = (rest & 3) * 128;
  const int n0 = (rest >> 2) * 64;

  // A DMA: 8 calls x 4 rows (256 B rows)
#pragma unroll
  for (int j = 0; j < 8; j++) {
    int row = w * 32 + j * 4 + (lane >> 4);
    int gs = (lane & 15) ^ (row & 7);
    load_lds16(&wo[(size_t)(o0 + row) * 128 + gs * 8],
               (void*)&A_lds[(w * 32 + j * 4) * 128]);
  }
  // B DMA: 4 calls x 4 rows
#pragma unroll
  for (int j = 0; j < 4; j++) {
    int row = w * 16 + j * 4 + (lane >> 4);
    int gs = (lane & 15) ^ (row & 7);
    load_lds16(&yt[((size_t)(b * 4096 + n0 + row)) * 128 + gs * 8],
               (void*)&B_lds[(w * 16 + j * 4) * 128]);
  }
  __syncthreads();

  f32x4 acc[2][4];
#pragma unroll
  for (int i = 0; i < 2; i++)
#pragma unroll
    for (int j = 0; j < 4; j++) acc[i][j] = (f32x4)0.f;
#pragma unroll
  for (int ks = 0; ks < 4; ks++) {
    short8 a0 = *(const short8*)&A_lds[sw(w * 32 + l15, ks * 32 + quad * 8, 128)];
    short8 a1 = *(const short8*)&A_lds[sw(w * 32 + 16 + l15, ks * 32 + quad * 8, 128)];
#pragma unroll
    for (int ns = 0; ns < 4; ns++) {
      short8 bb = *(const short8*)&B_lds[sw(ns * 16 + l15, ks * 32 + quad * 8, 128)];
      acc[0][ns] = __builtin_amdgcn_mfma_f32_16x16x32_bf16(a0, bb, acc[0][ns], 0, 0, 0);
      acc[1][ns] = __builtin_amdgcn_mfma_f32_16x16x32_bf16(a1, bb, acc[1][ns], 0, 0, 0);
    }
  }
#pragma unroll
  for (int ms = 0; ms < 2; ms++) {
    int o = o0 + w * 32 + ms * 16 + quad * 4;
#pragma unroll
    for (int ns = 0; ns < 4; ns++) {
      int n = n0 + ns * 16 + l15;
#pragma unroll
      for (int r = 0; r < 4; r++) {
        size_t off = ((size_t)(b * 512 + o + r)) * 4096 + n;
        out[off] = x[off] + acc[ms][ns][r];
      }
    }
  }
}

extern "C" void kernel_launch(void* const* d_in, const int* in_sizes, int n_in,
                              void* d_out, int out_size, void* d_ws, size_t ws_size,
                              hipStream_t stream) {
  const float* x = (const float*)d_in[0];
  const float* w_in = (const float*)d_in[1];
  const float* w_out = (const float*)d_in[2];
  float* out = (float*)d_out;

  unsigned short* aq = (unsigned short*)d_ws;                 // 8*4096*128
  unsigned short* Kf = aq + (size_t)8 * 4096 * 128;           // 8*64*8192
  unsigned short* Vf = Kf + (size_t)8 * 64 * 8192;            // 8*64*8192
  unsigned short* yt = Vf + (size_t)8 * 64 * 8192;            // 8*4096*128
  unsigned short* wi = yt + (size_t)8 * 4096 * 128;           // 384*512
  unsigned short* wo = wi + (size_t)384 * 512;                // 512*128

  k_prep<<<128, 256, 0, stream>>>(w_in, w_out, wi, wo);
  k_proj<<<dim3(64, 8), 256, 0, stream>>>(x, wi, aq, Kf, Vf);
  k_attn<<<dim3(256), 512, 0, stream>>>(aq, Kf, Vf, yt);
  k_out<<<2048, 256, 0, stream>>>(x, wo, yt, out);
}

// Round 11
// 210.223 us; speedup vs baseline: 1.0913x; 1.0054x over previous
//
#include <hip/hip_runtime.h>

// NonLocalBlock: B=8, C=512, N=4096 (64x64), CR=128.
// ws layout (bf16):
//   aq [8][4096][128]      emb_a token-major (Q reads; log2e pre-folded via wi)
//   Kf [8][64][8192]       K fragment-image per 64-key tile (chunk=1KB, lane-linear)
//   Vf [8][64][8192]       V fragment-image (see k_proj epilogue)
//   wf [128][512]          w_out fragment-image: chunk (ot*4+ks), lane (o&15)+quad*16,
//                          elem e: wo[ot*16+(l&15)][ks*32+(l>>4)*8+e]
//   wi [384][512]          bf16 w_in (emb_a rows pre-scaled by log2e)
// k_out is FUSED into k_attn's epilogue (out = x + Wo·y per 128-token block):
// k_attn is 1 block/CU by grid construction, so 99 KB dynamic LDS costs zero
// occupancy; wf panels stage over the dead K/V loop region.

typedef __attribute__((ext_vector_type(8))) short short8;
typedef __attribute__((ext_vector_type(4))) float f32x4;
typedef __attribute__((ext_vector_type(16))) float f32x16;
typedef __attribute__((ext_vector_type(2))) unsigned int uint2v;

__device__ inline unsigned bfr(float f) {   // bf16 round-half-up, result in high half
  union { float f; unsigned u; } v; v.f = f;
  return v.u + 0x8000u;
}
__device__ inline unsigned short f2bf(float f) { return (unsigned short)(bfr(f) >> 16); }
// pack2(a,b) -> [bf16(a) lo, bf16(b) hi] : 2 adds + 1 v_perm_b32
__device__ inline unsigned pack2(float a, float b) {
  return __builtin_amdgcn_perm(bfr(b), bfr(a), 0x07060302u);
}
// single-op packed f32->bf16 (RNE) for the hot loop
__device__ inline unsigned cvtpk(float a, float b) {
  unsigned r;
  asm("v_cvt_pk_bf16_f32 %0, %1, %2" : "=v"(r) : "v"(a), "v"(b));
  return r;
}
// XOR-swizzled LDS index (halves). 16B granules: phys = g ^ (row&7).
__device__ inline int sw(int row, int col, int stride_halves) {
  return row * stride_halves + ((((col >> 3) ^ (row & 7)) << 3) | (col & 7));
}
// async global->LDS DMA, 16B per lane; lds dest = wave-uniform base + lane*16
__device__ inline void load_lds16(const void* g, void* l) {
  __builtin_amdgcn_global_load_lds(
      (const __attribute__((address_space(1))) unsigned int*)g,
      (__attribute__((address_space(3))) unsigned int*)l, 16, 0, 0);
}

// ---------------- kernel 0: weight precompute fp32 -> bf16 -------------------------
// w_in -> wi (emb_a rows x log2e). w_out -> wf FRAGMENT-IMAGE (A-frag lane-linear,
// so k_attn's fused out-projection DMAs 1 KB contiguous and reads conflict-free).
__global__ __launch_bounds__(256) void k_prep(const float* __restrict__ w_in,
                                              const float* __restrict__ w_out,
                                              unsigned short* __restrict__ wi,
                                              unsigned short* __restrict__ wf) {
  int i = blockIdx.x * 256 + threadIdx.x;   // 8 floats per thread; 32768 threads
  if (i < 24576) {
    int base = i * 8;
    float s = (base < 128 * 512) ? 1.4426950408889634f : 1.0f;  // emb_a rows only
    float4 d0 = *(const float4*)&w_in[base];
    float4 d1 = *(const float4*)&w_in[base + 4];
    d0.x *= s; d0.y *= s; d0.z *= s; d0.w *= s;
    d1.x *= s; d1.y *= s; d1.z *= s; d1.w *= s;
    uint4 p;
    p.x = pack2(d0.x, d0.y); p.y = pack2(d0.z, d0.w);
    p.z = pack2(d1.x, d1.y); p.w = pack2(d1.z, d1.w);
    *(uint4*)&wi[base] = p;
  } else {
    int base = (i - 24576) * 8;             // linear idx in w_out [512 o][128 c]
    int o = base >> 7, c0 = base & 127;     // c0 multiple of 8
    float4 d0 = *(const float4*)&w_out[base];
    float4 d1 = *(const float4*)&w_out[base + 4];
    uint4 p;
    p.x = pack2(d0.x, d0.y); p.y = pack2(d0.z, d0.w);
    p.z = pack2(d1.x, d1.y); p.w = pack2(d1.z, d1.w);
    int chunk = (o >> 4) * 4 + (c0 >> 5);
    int lane = (o & 15) + ((c0 >> 3) & 3) * 16;
    *(uint4*)&wf[chunk * 512 + lane * 8] = p;
  }
}

// ---------------- kernel 1: in-projection GEMM (M=384, K=512, N=4096, per batch) ----
// ONE block per 64-token tile computes ALL 384 outputs (round-4 structure). The
// epilogue writes K/V directly in the attn fragment-image layout.
__global__ __launch_bounds__(256, 2) void k_proj(const float* __restrict__ x,
                                                 const unsigned short* __restrict__ wi,
                                                 unsigned short* __restrict__ aq,
                                                 unsigned short* __restrict__ Kf,
                                                 unsigned short* __restrict__ Vf) {
  __shared__ unsigned short A_lds[384 * 64];   // [384 o][64 c], swizzled (48 KB)
  __shared__ unsigned short B_lds[64 * 64];    // [64 n][64 c], swizzled (8 KB)
  const int t = threadIdx.x;
  const int lane = t & 63;
  const int w = t >> 6;
  const int l15 = lane & 15;
  const int quad = lane >> 4;
  const int tl = blockIdx.x;      // 64-token tile index
  const int n0 = tl * 64;
  const int b = blockIdx.y;
  const int ch8g = t >> 5;        // 0..7: 8-channel group for B staging
  const int tp = t & 31;          // 0..31: token pair

  f32x4 acc[6][4];
#pragma unroll
  for (int i = 0; i < 6; i++)
#pragma unroll
    for (int j = 0; j < 4; j++) acc[i][j] = (f32x4)0.f;

  // prologue: B panel for k0=0
  float2 d[8];
#pragma unroll
  for (int j = 0; j < 8; j++)
    d[j] = *(const float2*)&x[((size_t)(b * 512 + ch8g * 8 + j)) * 4096 + n0 + tp * 2];

  for (int k0 = 0; k0 < 512; k0 += 64) {
    // stage A via DMA: 96 rows per wave, 12 calls x 8 rows (128 B rows)
#pragma unroll
    for (int j = 0; j < 12; j++) {
      int row = w * 96 + j * 8 + (lane >> 3);
      int gs = (lane & 7) ^ (row & 7);
      load_lds16(&wi[(size_t)row * 512 + k0 + gs * 8],
                 (void*)&A_lds[(w * 96 + j * 8) * 64]);
    }
    // stage B micro-transpose from regs: 8 channels x 2 tokens per thread
#pragma unroll
    for (int i = 0; i < 2; i++) {
      int r = tp * 2 + i;
      uint4 pv;
      if (i == 0) {
        pv.x = pack2(d[0].x, d[1].x); pv.y = pack2(d[2].x, d[3].x);
        pv.z = pack2(d[4].x, d[5].x); pv.w = pack2(d[6].x, d[7].x);
      } else {
        pv.x = pack2(d[0].y, d[1].y); pv.y = pack2(d[2].y, d[3].y);
        pv.z = pack2(d[4].y, d[5].y); pv.w = pack2(d[6].y, d[7].y);
      }
      *(uint4*)&B_lds[sw(r, ch8g * 8, 64)] = pv;
    }
    // prefetch next B panel (overlaps barrier + MFMA below)
    if (k0 + 64 < 512) {
#pragma unroll
      for (int j = 0; j < 8; j++)
        d[j] = *(const float2*)&x[((size_t)(b * 512 + k0 + 64 + ch8g * 8 + j)) * 4096 + n0 + tp * 2];
    }
    __syncthreads();   // drains DMA (vmcnt) + B ds_writes (lgkm)
#pragma unroll
    for (int kk = 0; kk < 64; kk += 32) {
      short8 a[6];
#pragma unroll
      for (int m = 0; m < 6; m++)
        a[m] = *(const short8*)&A_lds[sw(w * 96 + m * 16 + l15, kk + quad * 8, 64)];
#pragma unroll
      for (int ns = 0; ns < 4; ns++) {
        short8 bb = *(const short8*)&B_lds[sw(ns * 16 + l15, kk + quad * 8, 64)];
#pragma unroll
        for (int m = 0; m < 6; m++)
          acc[m][ns] = __builtin_amdgcn_mfma_f32_16x16x32_bf16(a[m], bb, acc[m][ns], 0, 0, 0);
      }
    }
    __syncthreads();
  }
  // epilogue: o<128 -> aq (token-major); 128..255 -> Kf fragment-image (uint2);
  //           o>=256 -> Vf fragment-image (scalar). Boundaries are wave-uniform.
  const size_t tbase = ((size_t)(b * 64 + tl)) * 8192;
#pragma unroll
  for (int m = 0; m < 6; m++) {
    int o = w * 96 + m * 16 + quad * 4;
    if (o < 128) {
#pragma unroll
      for (int ns = 0; ns < 4; ns++) {
        int n = n0 + ns * 16 + l15;
        uint2 p;
        p.x = pack2(acc[m][ns][0], acc[m][ns][1]);
        p.y = pack2(acc[m][ns][2], acc[m][ns][3]);
        *(uint2*)&aq[((size_t)(b * 4096 + n)) * 128 + o] = p;
      }
    } else if (o < 256) {
      int c = o - 128;                       // 0..127, aligned 4
      int ksc = c >> 4, hk = (c >> 3) & 1, e0 = c & 7;   // e0 in {0,4}
#pragma unroll
      for (int ns = 0; ns < 4; ns++) {
        int key = ns * 16 + l15;             // 0..63 within tile
        int ck = (key >> 5) * 8 + ksc;
        int lane_k = hk * 32 + (key & 31);
        uint2 p;
        p.x = pack2(acc[m][ns][0], acc[m][ns][1]);
        p.y = pack2(acc[m][ns][2], acc[m][ns][3]);
        *(uint2*)&Kf[tbase + ck * 512 + lane_k * 8 + e0] = p;
      }
    } else {
      int cb = o - 256;                      // 0..127, aligned 4
#pragma unroll
      for (int ns = 0; ns < 4; ns++) {
        int key = ns * 16 + l15;
        int g8 = key >> 3;                   // key granule 0..7
        int e = key & 7;
        size_t kb = tbase + (size_t)((g8 & 1) * 32) * 8 + e + (size_t)(g8 >> 1) * 512;
#pragma unroll
        for (int r = 0; r < 4; r++) {
          int c = cb + r;
          Vf[kb + (size_t)(c >> 5) * 4 * 512 + (size_t)(c & 31) * 8] = f2bf(acc[m][ns][r]);
        }
      }
    }
  }
}

// ---------------- kernel 2: flash attention + FUSED out-projection ----------------
// Loop: round-10 deferred-PV pipeline (S_it -> PV_{it-1} -> softmax_it), K one-ahead
// dbuf, V same-iter dbuf, fragment-image linear DMA, conflict-free LDS.
// Epilogue: single-pass merge (128 q) into Pbuf, then out[:, o, q0..q0+127] =
// x + Wo·y computed in-block: 4 o-passes x {stage 32KB wf panel over dead loop LDS,
// mini-GEMM (A=wf frags, B=Pbuf rows), store}. Eliminates k_out + yt roundtrip.
// Dynamic LDS 101376 B; grid 256 = 1 block/CU so the extra LDS is occupancy-free.
__global__ __launch_bounds__(512, 1) void k_attn(const unsigned short* __restrict__ aq,
                                                 const unsigned short* __restrict__ Kf,
                                                 const unsigned short* __restrict__ Vf,
                                                 const unsigned short* __restrict__ wf,
                                                 const float* __restrict__ x,
                                                 float* __restrict__ out) {
  extern __shared__ unsigned short smem_h[];
  // loop (bytes): K bufs [0,16384),[16384,32768); V bufs [32768,49152),[49152,65536)
  // epilogue (bytes): Obuf [0,66048) f32 [128 q][129]; lsumbuf [66048,66560) f32[128];
  //   Pbuf [66560,101376) u32 [128 q][68] (stride 68 -> 16B-aligned rows, ~2-way banks);
  //   wf panel reuses [0,32768) after Obuf is dead.
  float* Obuf = (float*)smem_h;
  float* lsumbuf = (float*)((char*)smem_h + 66048);
  unsigned* Pbuf = (unsigned*)((char*)smem_h + 66560);

  const int t = threadIdx.x;
  const int lane = t & 63;
  const int w = t >> 6;        // 0..7
  const int wr = w & 1;        // key half
  const int wc = w >> 1;       // q tile (0..3), 32 q each
  const int l31 = lane & 31;
  const int h = lane >> 5;
  const int l15 = lane & 15;
  const int quad = lane >> 4;
  const int b = blockIdx.x & 7;            // XCD-locality: batch -> XCD
  const int q0 = (blockIdx.x >> 3) * 128;

  // Q fragments (B operand), loop-invariant
  short8 qf[8];
  {
    const unsigned short* qp = &aq[((size_t)(b * 4096 + q0 + wc * 32 + l31)) * 128 + h * 8];
#pragma unroll
    for (int ks = 0; ks < 8; ks++) qf[ks] = *(const short8*)&qp[ks * 16];
  }

  auto dma_k = [&](int tl, int buf) {
    unsigned short* Kb = smem_h + buf * 8192;
    const unsigned short* Ks = &Kf[((size_t)(b * 64 + tl)) * 8192];
#pragma unroll
    for (int j = 0; j < 2; j++) {
      int ck = w * 2 + j;
      load_lds16(&Ks[ck * 512 + lane * 8], (void*)&Kb[ck * 512]);
    }
  };
  auto dma_v = [&](int tl, int buf) {
    unsigned short* Vb = smem_h + 16384 + buf * 8192;
    const unsigned short* Vs = &Vf[((size_t)(b * 64 + tl)) * 8192];
#pragma unroll
    for (int j = 0; j < 2; j++) {
      int cv = w * 2 + j;
      load_lds16(&Vs[cv * 512 + lane * 8], (void*)&Vb[cv * 512]);
    }
  };

  f32x16 O[4];
#pragma unroll
  for (int i = 0; i < 4; i++) O[i] = (f32x16)0.f;
  float ls0 = 0.f, ls1 = 0.f, ls2 = 0.f, ls3 = 0.f;
  short8 pfP[2];                                       // P fragments of tile it-1

  auto computeS = [&](const unsigned short* Kc) -> f32x16 {
    f32x16 accS = (f32x16)0.f;
#pragma unroll
    for (int ks = 0; ks < 8; ks++) {
      short8 ak = *(const short8*)&Kc[(wr * 8 + ks) * 512 + lane * 8];
      accS = __builtin_amdgcn_mfma_f32_32x32x16_bf16(ak, qf[ks], accS, 0, 0, 0);
    }
    return accS;
  };
  auto computePV = [&](const unsigned short* Vc, const short8 pf[2]) {
#pragma unroll
    for (int ct = 0; ct < 4; ct++) {
#pragma unroll
      for (int f = 0; f < 2; f++) {
        short8 av = *(const short8*)&Vc[(ct * 4 + wr * 2 + f) * 512 + lane * 8];
        O[ct] = __builtin_amdgcn_mfma_f32_32x32x16_bf16(av, pf[f], O[ct], 0, 0, 0);
      }
    }
  };
  auto softmax = [&](const f32x16& accS, short8 pf[2]) {
    float ps[16];
#pragma unroll
    for (int r = 0; r < 16; r++) ps[r] = __builtin_amdgcn_exp2f(accS[r]);
    ls0 += ps[0] + ps[4];  ls1 += ps[1] + ps[5];
    ls2 += ps[2] + ps[6];  ls3 += ps[3] + ps[7];
    ls0 += ps[8] + ps[12]; ls1 += ps[9] + ps[13];
    ls2 += ps[10] + ps[14]; ls3 += ps[11] + ps[15];
    unsigned u[8];
#pragma unroll
    for (int i = 0; i < 8; i++) u[i] = cvtpk(ps[2 * i], ps[2 * i + 1]);
#pragma unroll
    for (int f = 0; f < 2; f++) {
      uint2v r02 = __builtin_amdgcn_permlane32_swap(u[4 * f + 0], u[4 * f + 2], false, false);
      uint2v r13 = __builtin_amdgcn_permlane32_swap(u[4 * f + 1], u[4 * f + 3], false, false);
      union { unsigned uu[4]; short8 s; } cv;
      cv.uu[0] = r02[0]; cv.uu[1] = r13[0]; cv.uu[2] = r02[1]; cv.uu[3] = r13[1];
      pf[f] = cv.s;
    }
  };

  // prologue: K tile 0 + V tile 0
  dma_k(0, 0);
  dma_v(0, 0);
  __syncthreads();

  // peeled iter 0: S_0 + softmax_0 (no PV yet); stage K tile 1
  {
    dma_k(1, 1);
    __builtin_amdgcn_s_setprio(1);
    f32x16 accS = computeS(smem_h);
    __builtin_amdgcn_s_setprio(0);
    softmax(accS, pfP);
    __syncthreads();
  }

  for (int it = 1; it < 64; ++it) {
    if (it < 63) dma_k(it + 1, (it + 1) & 1);   // K one ahead
    dma_v(it, it & 1);                          // V same-iter (read next iter)
    const unsigned short* Kc = smem_h + (it & 1) * 8192;
    const unsigned short* Vp = smem_h + 16384 + ((it - 1) & 1) * 8192;
    __builtin_amdgcn_s_setprio(1);
    f32x16 accS = computeS(Kc);      // S for tile it
    computePV(Vp, pfP);              // PV for tile it-1 (independent of softmax)
    __builtin_amdgcn_s_setprio(0);
    softmax(accS, pfP);              // VALU overlaps the PV MFMA block
    __syncthreads();                 // buffer reuse + DMA drain
  }

  // final PV for tile 63 (V buf 1; staged at it=63, drained by its barrier)
  {
    __builtin_amdgcn_s_setprio(1);
    computePV(smem_h + 16384 + 8192, pfP);
    __builtin_amdgcn_s_setprio(0);
  }
  __syncthreads();   // all K/V LDS reads done before Obuf aliases the region

  // ---- merge key-half partials into Pbuf (single pass, all 128 q) ----
  float lsum = (ls0 + ls1) + (ls2 + ls3);
  lsum += __shfl_xor(lsum, 32);
  const int q = wc * 32 + l31;                 // 0..127
  if (wr == 0) {
#pragma unroll
    for (int ct = 0; ct < 4; ct++)
#pragma unroll
      for (int r = 0; r < 16; r++) {
        int c = ct * 32 + (r & 3) + 8 * (r >> 2) + 4 * h;
        Obuf[q * 129 + c] = O[ct][r];
      }
    if (h == 0) lsumbuf[q] = lsum;
  }
  __syncthreads();
  if (wr == 1) {
    float linv = 1.f / (lsum + lsumbuf[q]);
#pragma unroll
    for (int ct = 0; ct < 4; ct++)
#pragma unroll
      for (int r = 0; r < 16; r += 2) {
        int c = ct * 32 + (r & 3) + 8 * (r >> 2) + 4 * h;
        float v0 = (Obuf[q * 129 + c] + O[ct][r]) * linv;
        float v1 = (Obuf[q * 129 + c + 1] + O[ct][r + 1]) * linv;
        Pbuf[q * 68 + (c >> 1)] = pack2(v0, v1);
      }
  }
  __syncthreads();   // Pbuf complete; Obuf dead -> wf panel may reuse [0,32768)

  // ---- fused out-projection: out[b, o, q0+n] = x + sum_c wo[o][c]*y[n][c] ----
  // 4 passes of 128 o. Wave w: ot_local = (w&3)*2 + {0,1}, nt = (w>>2)*4 + {0..3}.
  unsigned short* Wp = smem_h;                 // [32 chunks][512 halves] = 32 KB
  for (int p = 0; p < 4; ++p) {
    // stage wf chunks p*32 .. p*32+31 (1 KB each, linear both sides)
#pragma unroll
    for (int j = 0; j < 4; j++) {
      int cl = w * 4 + j;
      load_lds16(&wf[(p * 32 + cl) * 512 + lane * 8], (void*)&Wp[cl * 512]);
    }
    __syncthreads();   // panel ready (also fences prev pass's Pbuf reads vs nothing)

    f32x4 acc[2][4];
#pragma unroll
    for (int i = 0; i < 2; i++)
#pragma unroll
      for (int j = 0; j < 4; j++) acc[i][j] = (f32x4)0.f;
#pragma unroll
    for (int ks = 0; ks < 4; ks++) {
      short8 a[2];
#pragma unroll
      for (int i = 0; i < 2; i++)
        a[i] = *(const short8*)&Wp[(((w & 3) * 2 + i) * 4 + ks) * 512 + lane * 8];
#pragma unroll
      for (int nt = 0; nt < 4; nt++) {
        int token = ((w >> 2) * 4 + nt) * 16 + l15;
        short8 bb = *(const short8*)&Pbuf[token * 68 + ks * 16 + quad * 4];
#pragma unroll
        for (int i = 0; i < 2; i++)
          acc[i][nt] = __builtin_amdgcn_mfma_f32_16x16x32_bf16(a[i], bb, acc[i][nt], 0, 0, 0);
      }
    }
    // store: D col = token (l15), row o = quad*4 + r
#pragma unroll
    for (int i = 0; i < 2; i++) {
      int o = p * 128 + ((w & 3) * 2 + i) * 16 + quad * 4;
#pragma unroll
      for (int nt = 0; nt < 4; nt++) {
        int n = q0 + ((w >> 2) * 4 + nt) * 16 + l15;
#pragma unroll
        for (int r = 0; r < 4; r++) {
          size_t off = ((size_t)(b * 512 + o + r)) * 4096 + n;
          out[off] = x[off] + acc[i][nt][r];
        }
      }
    }
    __syncthreads();   // all Wp reads done before next pass restages
  }
}

extern "C" void kernel_launch(void* const* d_in, const int* in_sizes, int n_in,
                              void* d_out, int out_size, void* d_ws, size_t ws_size,
                              hipStream_t stream) {
  const float* x = (const float*)d_in[0];
  const float* w_in = (const float*)d_in[1];
  const float* w_out = (const float*)d_in[2];
  float* out = (float*)d_out;

  unsigned short* aq = (unsigned short*)d_ws;                 // 8*4096*128
  unsigned short* Kf = aq + (size_t)8 * 4096 * 128;           // 8*64*8192
  unsigned short* Vf = Kf + (size_t)8 * 64 * 8192;            // 8*64*8192
  unsigned short* wf = Vf + (size_t)8 * 64 * 8192;            // 128*512
  unsigned short* wi = wf + (size_t)128 * 512;                // 384*512

  static bool attr_set = false;
  if (!attr_set) {
    hipFuncSetAttribute((const void*)k_attn,
                        hipFuncAttributeMaxDynamicSharedMemorySize, 101376);
    attr_set = true;
  }

  k_prep<<<128, 256, 0, stream>>>(w_in, w_out, wi, wf);
  k_proj<<<dim3(64, 8), 256, 0, stream>>>(x, wi, aq, Kf, Vf);
  k_attn<<<dim3(256), 512, 101376, stream>>>(aq, Kf, Vf, wf, x, out);
}